// Round 3
// baseline (405.649 us; speedup 1.0000x reference)
//
#include <hip/hip_runtime.h>
#include <math.h>

#define NTOK 9216      // 96*96 tokens
#define CIN  32        // inner channels
#define CC   64        // outer channels
#define NCH1 8         // phase1 n-chunks
#define NCH2 6         // phase2 m-chunks
#define NT1  72        // n-tiles (16-wide) per phase1 chunk: 576/8
#define MS2  48        // m-steps (32-wide) per phase2 chunk: 9216/6/32
#define SHIFT2 6.4548225555f   // 12 - ln(256)

typedef _Float16 half8 __attribute__((ext_vector_type(8)));
typedef float    f32x4 __attribute__((ext_vector_type(4)));

// ---------------- tiled conv 3x3 stride 2 pad 1, LDS-staged ----------------
// block: TS*TS threads = one output spatial tile; blockIdx.y = oc-group of OCG.
// Input tile (2TS+1)^2 staged in ci-groups of CIS. Weights read via uniform
// (scalar) loads from global.
template<int HIN, int HOUT, int TS, int OCG, int CIS, int LRELU>
__global__ void conv3x3_tile(const float* __restrict__ in, const float* __restrict__ w,
                             const float* __restrict__ b, float* __restrict__ out) {
    constexpr int ITS = 2 * TS + 1;
    constexpr int LW  = ITS + 1;
    constexpr int NT  = TS * TS;
    __shared__ float lds[CIS][ITS * LW];
    const int t = threadIdx.x;
    const int nx = HOUT / TS;
    const int bx = blockIdx.x % nx, by = blockIdx.x / nx;
    const int ocg = blockIdx.y;
    const int OH0 = TS * by, OW0 = TS * bx;
    const int IH0 = 2 * OH0 - 1, IW0 = 2 * OW0 - 1;
    const int ly = t / TS, lx = t % TS;
    float acc[OCG];
    #pragma unroll
    for (int o = 0; o < OCG; ++o) acc[o] = b[ocg * OCG + o];
    for (int cig = 0; cig < CC; cig += CIS) {
        __syncthreads();
        for (int idx = t; idx < CIS * ITS * ITS; idx += NT) {
            int ci = idx / (ITS * ITS), rem = idx % (ITS * ITS);
            int r = rem / ITS, c = rem % ITS;
            int ih = IH0 + r, iw = IW0 + c;
            float v = 0.f;
            if (ih >= 0 && ih < HIN && iw >= 0 && iw < HIN)
                v = in[(cig + ci) * HIN * HIN + ih * HIN + iw];
            lds[ci][r * LW + c] = v;
        }
        __syncthreads();
        for (int ci = 0; ci < CIS; ++ci) {
            float v[9];
            #pragma unroll
            for (int kh = 0; kh < 3; ++kh)
                #pragma unroll
                for (int kw = 0; kw < 3; ++kw)
                    v[kh * 3 + kw] = lds[ci][(2 * ly + kh) * LW + 2 * lx + kw];
            const float* wp = w + (ocg * OCG) * CC * 9 + (cig + ci) * 9;
            #pragma unroll
            for (int o = 0; o < OCG; ++o)
                #pragma unroll
                for (int k = 0; k < 9; ++k)
                    acc[o] = fmaf(v[k], wp[o * CC * 9 + k], acc[o]);
        }
    }
    const int oh = OH0 + ly, ow = OW0 + lx;
    #pragma unroll
    for (int o = 0; o < OCG; ++o) {
        float a = acc[o];
        if (LRELU) a = a >= 0.f ? a : 0.2f * a;
        out[(ocg * OCG + o) * HOUT * HOUT + oh * HOUT + ow] = a;
    }
}

// ---------------- bilinear 12->96 upsample + sigmoid gate ----------------
__global__ void gate_kernel(const float* __restrict__ x, const float* __restrict__ y3,
                            float* __restrict__ xg) {
    int idx = blockIdx.x * 256 + threadIdx.x;   // 64*96*96
    int c = idx / (96 * 96);
    int p = idx % (96 * 96);
    int h = p / 96, w = p % 96;
    float fh = (h + 0.5f) * 0.125f - 0.5f;
    float fw = (w + 0.5f) * 0.125f - 0.5f;
    int h0 = (int)floorf(fh); float ah = fh - (float)h0;
    int w0 = (int)floorf(fw); float aw = fw - (float)w0;
    int h0c = min(max(h0, 0), 11), h1c = min(max(h0 + 1, 0), 11);
    int w0c = min(max(w0, 0), 11), w1c = min(max(w0 + 1, 0), 11);
    const float* yp = y3 + c * 144;
    float v = (1.f - ah) * ((1.f - aw) * yp[h0c * 12 + w0c] + aw * yp[h0c * 12 + w1c])
            +         ah * ((1.f - aw) * yp[h1c * 12 + w0c] + aw * yp[h1c * 12 + w1c]);
    float sg = 1.f / (1.f + __expf(-v));
    xg[idx] = sg * x[idx];
}

// ---------------- three 1x1 convs (g, theta, phi) ----------------
__global__ void conv1x1_3(const float* __restrict__ xg,
                          const float* __restrict__ gw, const float* __restrict__ gb,
                          const float* __restrict__ thw, const float* __restrict__ thb,
                          const float* __restrict__ phw, const float* __restrict__ phb,
                          float* __restrict__ gx, float* __restrict__ tx, float* __restrict__ px) {
    int which = blockIdx.z;
    const float* w  = which == 0 ? gw : (which == 1 ? thw : phw);
    const float* bb = which == 0 ? gb : (which == 1 ? thb : phb);
    float* outp     = which == 0 ? gx : (which == 1 ? tx : px);
    int ci = blockIdx.y;
    int n = blockIdx.x * 256 + threadIdx.x;
    float acc = bb[ci];
    #pragma unroll 8
    for (int c = 0; c < CC; ++c)
        acc = fmaf(w[ci * CC + c], xg[c * NTOK + n], acc);
    outp[ci * NTOK + n] = acc;
}

// ---------------- repack tx/px (f32 [32][NTOK]) -> fragment-packed f16 ----------------
__global__ void repackAB(const float* __restrict__ tx, const float* __restrict__ px,
                         _Float16* __restrict__ txF, _Float16* __restrict__ pxF) {
    const float* src = blockIdx.y ? px : tx;
    _Float16* dst    = blockIdx.y ? pxF : txF;
    int gid = blockIdx.x * 256 + threadIdx.x;   // 576 tiles * 64 lanes = 36864
    int t = gid >> 6, l = gid & 63;
    int n = t * 16 + (l & 15);
    int khi = (l >> 4) * 4;
    half8 v;
    #pragma unroll
    for (int e = 0; e < 8; ++e) {
        int c = (e >> 2) * 16 + khi + (e & 3);
        v[e] = (_Float16)src[c * NTOK + n];
    }
    *(half8*)(dst + gid * 8) = v;
}

// ---------------- repack gx -> B-fragment-packed f16: [mt32][ct2][64][8] ----------------
__global__ void repackG(const float* __restrict__ gx, _Float16* __restrict__ gxF) {
    __shared__ float lds[CIN][65];
    int m0 = blockIdx.x * 64;
    int tid = threadIdx.x;
    for (int idx = tid; idx < CIN * 64; idx += 256)
        lds[idx >> 6][idx & 63] = gx[(idx >> 6) * NTOK + m0 + (idx & 63)];
    __syncthreads();
    int mt = tid >> 7;            // 0..1 (m-32 subtile)
    int slot = tid & 127;
    int ct = slot >> 6;           // c-tile 0..1
    int l  = slot & 63;
    int khi = (l >> 4) * 4;
    int c = ct * 16 + (l & 15);
    half8 v;
    #pragma unroll
    for (int e = 0; e < 8; ++e) {
        int mloc = (e >> 2) * 16 + khi + (e & 3);
        v[e] = (_Float16)lds[c][mt * 32 + mloc];
    }
    int tile = (blockIdx.x * 2 + mt) * 2 + ct;
    *(half8*)(gxF + tile * 512 + l * 8) = v;
}

// ---------------- phase 1: D[m] = sum_n exp(s[n,m]-12), MFMA ----------------
__global__ __launch_bounds__(256) void phase1(const _Float16* __restrict__ txF,
                                              const _Float16* __restrict__ pxF,
                                              float* __restrict__ Dp) {
    int w = threadIdx.x >> 6, l = threadIdx.x & 63;
    int mtile = blockIdx.x * 4 + w;           // 0..575
    half8 pf = *(const half8*)(pxF + mtile * 512 + l * 8);
    f32x4 zero = {0.f, 0.f, 0.f, 0.f};
    float dsum[4] = {0.f, 0.f, 0.f, 0.f};
    int nt0 = blockIdx.y * NT1;
    for (int i = 0; i < NT1; ++i) {
        half8 tf = *(const half8*)(txF + (nt0 + i) * 512 + l * 8);
        f32x4 s = __builtin_amdgcn_mfma_f32_16x16x32_f16(pf, tf, zero, 0, 0, 0);
        #pragma unroll
        for (int r = 0; r < 4; ++r)
            dsum[r] += __expf(s[r] - 12.0f);
    }
    #pragma unroll
    for (int off = 1; off < 16; off <<= 1)
        #pragma unroll
        for (int r = 0; r < 4; ++r)
            dsum[r] += __shfl_xor(dsum[r], off);
    if ((l & 15) == 0) {
        int m = mtile * 16 + (l >> 4) * 4;
        #pragma unroll
        for (int r = 0; r < 4; ++r)
            Dp[blockIdx.y * NTOK + m + r] = dsum[r];
    }
}

// ---------------- merge D partials -> logD ----------------
__global__ void mergeD(const float* __restrict__ Dp, float* __restrict__ logD) {
    int m = blockIdx.x * 256 + threadIdx.x;
    float D = 0.f;
    #pragma unroll
    for (int ch = 0; ch < NCH1; ++ch) D += Dp[ch * NTOK + m];
    logD[m] = __logf(D);
}

// ---------------- phase 2: y2[c,n] = sum_m f[n,m] gx[c,m], MFMA ----------------
__global__ __launch_bounds__(256) void phase2(const _Float16* __restrict__ txF,
                                              const _Float16* __restrict__ pxF,
                                              const _Float16* __restrict__ gxF,
                                              const float* __restrict__ logD,
                                              float* __restrict__ y2p) {
    int w = threadIdx.x >> 6, l = threadIdx.x & 63;
    int ntile = blockIdx.x * 4 + w;           // 0..575
    half8 tf = *(const half8*)(txF + ntile * 512 + l * 8);
    int khi = (l >> 4) * 4;
    f32x4 zero = {0.f, 0.f, 0.f, 0.f};
    f32x4 acc0 = zero, acc1 = zero;
    int mbase = blockIdx.y * (NTOK / NCH2);
    for (int ms = 0; ms < MS2; ++ms) {
        int m0 = mbase + ms * 32;
        int mt16 = m0 >> 4;
        half8 pf0 = *(const half8*)(pxF + mt16 * 512 + l * 8);
        half8 pf1 = *(const half8*)(pxF + (mt16 + 1) * 512 + l * 8);
        f32x4 s0 = __builtin_amdgcn_mfma_f32_16x16x32_f16(pf0, tf, zero, 0, 0, 0);
        f32x4 s1 = __builtin_amdgcn_mfma_f32_16x16x32_f16(pf1, tf, zero, 0, 0, 0);
        f32x4 ld0 = *(const f32x4*)(logD + m0 + khi);
        f32x4 ld1 = *(const f32x4*)(logD + m0 + 16 + khi);
        half8 ff;
        #pragma unroll
        for (int r = 0; r < 4; ++r) {
            ff[r]     = (_Float16)__expf(s0[r] - SHIFT2 - ld0[r]);
            ff[4 + r] = (_Float16)__expf(s1[r] - SHIFT2 - ld1[r]);
        }
        int gt = (m0 >> 5) * 2;
        half8 gf0 = *(const half8*)(gxF + gt * 512 + l * 8);
        half8 gf1 = *(const half8*)(gxF + (gt + 1) * 512 + l * 8);
        acc0 = __builtin_amdgcn_mfma_f32_16x16x32_f16(ff, gf0, acc0, 0, 0, 0);
        acc1 = __builtin_amdgcn_mfma_f32_16x16x32_f16(ff, gf1, acc1, 0, 0, 0);
    }
    float* base = y2p + blockIdx.y * (CIN * NTOK);
    int n = ntile * 16 + khi;
    #pragma unroll
    for (int r = 0; r < 4; ++r) {
        base[(l & 15) * NTOK + n + r]        = acc0[r] * 0.00390625f;
        base[(16 + (l & 15)) * NTOK + n + r] = acc1[r] * 0.00390625f;
    }
}

// ---------------- merge y2 partials ----------------
__global__ void mergeY2(const float* __restrict__ y2p, float* __restrict__ att) {
    int idx = blockIdx.x * 256 + threadIdx.x;   // 32*9216
    float s = 0.f;
    #pragma unroll
    for (int ch = 0; ch < NCH2; ++ch) s += y2p[ch * (CIN * NTOK) + idx];
    att[idx] = s;
}

// ---------------- final 1x1 conv + residual ----------------
__global__ void final_conv(const float* __restrict__ att, const float* __restrict__ Ww,
                           const float* __restrict__ Wb, const float* __restrict__ xg,
                           float* __restrict__ out) {
    int co = blockIdx.y;
    int n = blockIdx.x * 256 + threadIdx.x;
    float acc = Wb[co];
    #pragma unroll
    for (int ci = 0; ci < CIN; ++ci)
        acc = fmaf(Ww[co * CIN + ci], att[ci * NTOK + n], acc);
    out[co * NTOK + n] = acc + xg[co * NTOK + n];
}

extern "C" void kernel_launch(void* const* d_in, const int* in_sizes, int n_in,
                              void* d_out, int out_size, void* d_ws, size_t ws_size,
                              hipStream_t stream) {
    const float* x   = (const float*)d_in[0];
    const float* d1w = (const float*)d_in[1];  const float* d1b = (const float*)d_in[2];
    const float* d2w = (const float*)d_in[3];  const float* d2b = (const float*)d_in[4];
    const float* d3w = (const float*)d_in[5];  const float* d3b = (const float*)d_in[6];
    const float* gw  = (const float*)d_in[7];  const float* gb  = (const float*)d_in[8];
    const float* thw = (const float*)d_in[9];  const float* thb = (const float*)d_in[10];
    const float* phw = (const float*)d_in[11]; const float* phb = (const float*)d_in[12];
    const float* Ww  = (const float*)d_in[13]; const float* Wb  = (const float*)d_in[14];
    float* out = (float*)d_out;

    float* W    = (float*)d_ws;
    float* xg   = W;                 // 589824
    float* y1   = W + 589824;        // 147456
    float* y2c  = W + 737280;        // 36864
    float* y3   = W + 774144;        // 9216
    float* txb  = W + 783360;        // 294912
    float* pxb  = W + 1078272;       // 294912
    float* gxb  = W + 1373184;       // 294912
    float* Dp   = W + 1668096;       // 8*9216 = 73728
    float* logD = W + 1741824;       // 9216
    float* att  = W + 1751040;       // 294912
    float* y2p  = W + 2045952;       // 6*294912 = 1769472
    _Float16* txF = (_Float16*)(W + 3815424);   // 294912 f16
    _Float16* pxF = (_Float16*)(W + 3962880);   // 294912 f16
    _Float16* gxF = (_Float16*)(W + 4110336);   // 294912 f16

    // gating branch (reads ORIGINAL x)
    conv3x3_tile<96, 48, 16, 4, 8, 1><<<dim3(9, 16), 256, 0, stream>>>(x,   d1w, d1b, y1);
    conv3x3_tile<48, 24, 24, 1, 4, 1><<<dim3(1, 64), 576, 0, stream>>>(y1,  d2w, d2b, y2c);
    conv3x3_tile<24, 12, 12, 1, 16, 0><<<dim3(1, 64), 144, 0, stream>>>(y2c, d3w, d3b, y3);
    gate_kernel<<<2304, 256, 0, stream>>>(x, y3, xg);

    // 1x1 projections (f32)
    conv1x1_3<<<dim3(36, CIN, 3), 256, 0, stream>>>(xg, gw, gb, thw, thb, phw, phb,
                                                    gxb, txb, pxb);
    // fragment repack to f16
    repackAB<<<dim3(144, 2), 256, 0, stream>>>(txb, pxb, txF, pxF);
    repackG<<<144, 256, 0, stream>>>(gxb, gxF);

    // attention via MFMA
    phase1<<<dim3(144, NCH1), 256, 0, stream>>>(txF, pxF, Dp);
    mergeD<<<36, 256, 0, stream>>>(Dp, logD);
    phase2<<<dim3(144, NCH2), 256, 0, stream>>>(txF, pxF, gxF, logD, y2p);
    mergeY2<<<1152, 256, 0, stream>>>(y2p, att);

    // output
    final_conv<<<dim3(36, CC), 256, 0, stream>>>(att, Ww, Wb, xg, out);
}

// Round 4
// 154.170 us; speedup vs baseline: 2.6312x; 2.6312x over previous
//
#include <hip/hip_runtime.h>
#include <math.h>

#define NTOK 9216      // 96*96 tokens
#define CIN  32        // inner channels
#define CC   64        // outer channels
#define NCH1 8         // phase1 n-chunks
#define NCH2 6         // phase2 m-chunks
#define NT1  72        // n-tiles (16-wide) per phase1 chunk: 576/8
#define MS2  48        // m-steps (32-wide) per phase2 chunk: 9216/6/32
#define SHIFT2 6.4548225555f   // 12 - ln(256)

typedef _Float16 half8 __attribute__((ext_vector_type(8)));
typedef float    f32x4 __attribute__((ext_vector_type(4)));

// ---------------- conv 3x3 stride 2 pad 1: partial over ci-groups ----------------
// grid: (pxBlocks, CC oc, CC/CIG groups). One thread per output pixel; each
// block reduces CIG input channels; partials merged by conv_merge.
template<int HIN, int HOUT, int CIG>
__global__ void conv3x3_part(const float* __restrict__ in, const float* __restrict__ w,
                             float* __restrict__ outp) {
    const int p = blockIdx.x * blockDim.x + threadIdx.x;
    if (p >= HOUT * HOUT) return;
    const int oc = blockIdx.y, grp = blockIdx.z;
    const int oh = p / HOUT, ow = p % HOUT;
    const int ci0 = grp * CIG;
    float acc = 0.f;
    #pragma unroll 4
    for (int ci = 0; ci < CIG; ++ci) {
        const float* ip = in + (ci0 + ci) * HIN * HIN;
        const float* wp = w + oc * CC * 9 + (ci0 + ci) * 9;
        #pragma unroll
        for (int kh = 0; kh < 3; ++kh) {
            int ih = oh * 2 - 1 + kh;
            bool okh = (unsigned)ih < (unsigned)HIN;
            #pragma unroll
            for (int kw = 0; kw < 3; ++kw) {
                int iw = ow * 2 - 1 + kw;
                float v = (okh && (unsigned)iw < (unsigned)HIN) ? ip[ih * HIN + iw] : 0.f;
                acc = fmaf(v, wp[kh * 3 + kw], acc);
            }
        }
    }
    outp[grp * (CC * HOUT * HOUT) + oc * HOUT * HOUT + p] = acc;
}

// ---------------- merge conv partials + bias + (leaky)relu ----------------
template<int NG, int HW, int LRELU>
__global__ void conv_merge(const float* __restrict__ parts, const float* __restrict__ b,
                           float* __restrict__ out) {
    int idx = blockIdx.x * 256 + threadIdx.x;   // CC*HW total
    int oc = idx / HW;
    float acc = b[oc];
    #pragma unroll
    for (int g = 0; g < NG; ++g)
        acc += parts[g * (CC * HW) + idx];
    if (LRELU) acc = acc >= 0.f ? acc : 0.2f * acc;
    out[idx] = acc;
}

// ---------------- bilinear 12->96 upsample + sigmoid gate ----------------
__global__ void gate_kernel(const float* __restrict__ x, const float* __restrict__ y3,
                            float* __restrict__ xg) {
    int idx = blockIdx.x * 256 + threadIdx.x;   // 64*96*96
    int c = idx / (96 * 96);
    int p = idx % (96 * 96);
    int h = p / 96, w = p % 96;
    float fh = (h + 0.5f) * 0.125f - 0.5f;
    float fw = (w + 0.5f) * 0.125f - 0.5f;
    int h0 = (int)floorf(fh); float ah = fh - (float)h0;
    int w0 = (int)floorf(fw); float aw = fw - (float)w0;
    int h0c = min(max(h0, 0), 11), h1c = min(max(h0 + 1, 0), 11);
    int w0c = min(max(w0, 0), 11), w1c = min(max(w0 + 1, 0), 11);
    const float* yp = y3 + c * 144;
    float v = (1.f - ah) * ((1.f - aw) * yp[h0c * 12 + w0c] + aw * yp[h0c * 12 + w1c])
            +         ah * ((1.f - aw) * yp[h1c * 12 + w0c] + aw * yp[h1c * 12 + w1c]);
    float sg = 1.f / (1.f + __expf(-v));
    xg[idx] = sg * x[idx];
}

// ---------------- three 1x1 convs (g, theta, phi) ----------------
__global__ void conv1x1_3(const float* __restrict__ xg,
                          const float* __restrict__ gw, const float* __restrict__ gb,
                          const float* __restrict__ thw, const float* __restrict__ thb,
                          const float* __restrict__ phw, const float* __restrict__ phb,
                          float* __restrict__ gx, float* __restrict__ tx, float* __restrict__ px) {
    int which = blockIdx.z;
    const float* w  = which == 0 ? gw : (which == 1 ? thw : phw);
    const float* bb = which == 0 ? gb : (which == 1 ? thb : phb);
    float* outp     = which == 0 ? gx : (which == 1 ? tx : px);
    int ci = blockIdx.y;
    int n = blockIdx.x * 256 + threadIdx.x;
    float acc = bb[ci];
    #pragma unroll 8
    for (int c = 0; c < CC; ++c)
        acc = fmaf(w[ci * CC + c], xg[c * NTOK + n], acc);
    outp[ci * NTOK + n] = acc;
}

// ---------------- repack tx/px (f32 [32][NTOK]) -> fragment-packed f16 ----------------
__global__ void repackAB(const float* __restrict__ tx, const float* __restrict__ px,
                         _Float16* __restrict__ txF, _Float16* __restrict__ pxF) {
    const float* src = blockIdx.y ? px : tx;
    _Float16* dst    = blockIdx.y ? pxF : txF;
    int gid = blockIdx.x * 256 + threadIdx.x;   // 576 tiles * 64 lanes = 36864
    int t = gid >> 6, l = gid & 63;
    int n = t * 16 + (l & 15);
    int khi = (l >> 4) * 4;
    half8 v;
    #pragma unroll
    for (int e = 0; e < 8; ++e) {
        int c = (e >> 2) * 16 + khi + (e & 3);
        v[e] = (_Float16)src[c * NTOK + n];
    }
    *(half8*)(dst + gid * 8) = v;
}

// ---------------- repack gx -> B-fragment-packed f16: [mt32][ct2][64][8] ----------------
__global__ void repackG(const float* __restrict__ gx, _Float16* __restrict__ gxF) {
    __shared__ float lds[CIN][65];
    int m0 = blockIdx.x * 64;
    int tid = threadIdx.x;
    for (int idx = tid; idx < CIN * 64; idx += 256)
        lds[idx >> 6][idx & 63] = gx[(idx >> 6) * NTOK + m0 + (idx & 63)];
    __syncthreads();
    int mt = tid >> 7;            // 0..1 (m-32 subtile)
    int slot = tid & 127;
    int ct = slot >> 6;           // c-tile 0..1
    int l  = slot & 63;
    int khi = (l >> 4) * 4;
    int c = ct * 16 + (l & 15);
    half8 v;
    #pragma unroll
    for (int e = 0; e < 8; ++e) {
        int mloc = (e >> 2) * 16 + khi + (e & 3);
        v[e] = (_Float16)lds[c][mt * 32 + mloc];
    }
    int tile = (blockIdx.x * 2 + mt) * 2 + ct;
    *(half8*)(gxF + tile * 512 + l * 8) = v;
}

// ---------------- phase 1: D[m] = sum_n exp(s[n,m]-12), MFMA ----------------
__global__ __launch_bounds__(256) void phase1(const _Float16* __restrict__ txF,
                                              const _Float16* __restrict__ pxF,
                                              float* __restrict__ Dp) {
    int w = threadIdx.x >> 6, l = threadIdx.x & 63;
    int mtile = blockIdx.x * 4 + w;           // 0..575
    half8 pf = *(const half8*)(pxF + mtile * 512 + l * 8);
    f32x4 zero = {0.f, 0.f, 0.f, 0.f};
    float dsum[4] = {0.f, 0.f, 0.f, 0.f};
    int nt0 = blockIdx.y * NT1;
    for (int i = 0; i < NT1; ++i) {
        half8 tf = *(const half8*)(txF + (nt0 + i) * 512 + l * 8);
        f32x4 s = __builtin_amdgcn_mfma_f32_16x16x32_f16(pf, tf, zero, 0, 0, 0);
        #pragma unroll
        for (int r = 0; r < 4; ++r)
            dsum[r] += __expf(s[r] - 12.0f);
    }
    #pragma unroll
    for (int off = 1; off < 16; off <<= 1)
        #pragma unroll
        for (int r = 0; r < 4; ++r)
            dsum[r] += __shfl_xor(dsum[r], off);
    if ((l & 15) == 0) {
        int m = mtile * 16 + (l >> 4) * 4;
        #pragma unroll
        for (int r = 0; r < 4; ++r)
            Dp[blockIdx.y * NTOK + m + r] = dsum[r];
    }
}

// ---------------- merge D partials -> logD ----------------
__global__ void mergeD(const float* __restrict__ Dp, float* __restrict__ logD) {
    int m = blockIdx.x * 256 + threadIdx.x;
    float D = 0.f;
    #pragma unroll
    for (int ch = 0; ch < NCH1; ++ch) D += Dp[ch * NTOK + m];
    logD[m] = __logf(D);
}

// ---------------- phase 2: y2[c,n] = sum_m f[n,m] gx[c,m], MFMA ----------------
__global__ __launch_bounds__(256) void phase2(const _Float16* __restrict__ txF,
                                              const _Float16* __restrict__ pxF,
                                              const _Float16* __restrict__ gxF,
                                              const float* __restrict__ logD,
                                              float* __restrict__ y2p) {
    int w = threadIdx.x >> 6, l = threadIdx.x & 63;
    int ntile = blockIdx.x * 4 + w;           // 0..575
    half8 tf = *(const half8*)(txF + ntile * 512 + l * 8);
    int khi = (l >> 4) * 4;
    f32x4 zero = {0.f, 0.f, 0.f, 0.f};
    f32x4 acc0 = zero, acc1 = zero;
    int mbase = blockIdx.y * (NTOK / NCH2);
    for (int ms = 0; ms < MS2; ++ms) {
        int m0 = mbase + ms * 32;
        int mt16 = m0 >> 4;
        half8 pf0 = *(const half8*)(pxF + mt16 * 512 + l * 8);
        half8 pf1 = *(const half8*)(pxF + (mt16 + 1) * 512 + l * 8);
        f32x4 s0 = __builtin_amdgcn_mfma_f32_16x16x32_f16(pf0, tf, zero, 0, 0, 0);
        f32x4 s1 = __builtin_amdgcn_mfma_f32_16x16x32_f16(pf1, tf, zero, 0, 0, 0);
        f32x4 ld0 = *(const f32x4*)(logD + m0 + khi);
        f32x4 ld1 = *(const f32x4*)(logD + m0 + 16 + khi);
        half8 ff;
        #pragma unroll
        for (int r = 0; r < 4; ++r) {
            ff[r]     = (_Float16)__expf(s0[r] - SHIFT2 - ld0[r]);
            ff[4 + r] = (_Float16)__expf(s1[r] - SHIFT2 - ld1[r]);
        }
        int gt = (m0 >> 5) * 2;
        half8 gf0 = *(const half8*)(gxF + gt * 512 + l * 8);
        half8 gf1 = *(const half8*)(gxF + (gt + 1) * 512 + l * 8);
        acc0 = __builtin_amdgcn_mfma_f32_16x16x32_f16(ff, gf0, acc0, 0, 0, 0);
        acc1 = __builtin_amdgcn_mfma_f32_16x16x32_f16(ff, gf1, acc1, 0, 0, 0);
    }
    float* base = y2p + blockIdx.y * (CIN * NTOK);
    int n = ntile * 16 + khi;
    #pragma unroll
    for (int r = 0; r < 4; ++r) {
        base[(l & 15) * NTOK + n + r]        = acc0[r] * 0.00390625f;
        base[(16 + (l & 15)) * NTOK + n + r] = acc1[r] * 0.00390625f;
    }
}

// ---------------- merge y2 partials ----------------
__global__ void mergeY2(const float* __restrict__ y2p, float* __restrict__ att) {
    int idx = blockIdx.x * 256 + threadIdx.x;   // 32*9216
    float s = 0.f;
    #pragma unroll
    for (int ch = 0; ch < NCH2; ++ch) s += y2p[ch * (CIN * NTOK) + idx];
    att[idx] = s;
}

// ---------------- final 1x1 conv + residual ----------------
__global__ void final_conv(const float* __restrict__ att, const float* __restrict__ Ww,
                           const float* __restrict__ Wb, const float* __restrict__ xg,
                           float* __restrict__ out) {
    int co = blockIdx.y;
    int n = blockIdx.x * 256 + threadIdx.x;
    float acc = Wb[co];
    #pragma unroll
    for (int ci = 0; ci < CIN; ++ci)
        acc = fmaf(Ww[co * CIN + ci], att[ci * NTOK + n], acc);
    out[co * NTOK + n] = acc + xg[co * NTOK + n];
}

extern "C" void kernel_launch(void* const* d_in, const int* in_sizes, int n_in,
                              void* d_out, int out_size, void* d_ws, size_t ws_size,
                              hipStream_t stream) {
    const float* x   = (const float*)d_in[0];
    const float* d1w = (const float*)d_in[1];  const float* d1b = (const float*)d_in[2];
    const float* d2w = (const float*)d_in[3];  const float* d2b = (const float*)d_in[4];
    const float* d3w = (const float*)d_in[5];  const float* d3b = (const float*)d_in[6];
    const float* gw  = (const float*)d_in[7];  const float* gb  = (const float*)d_in[8];
    const float* thw = (const float*)d_in[9];  const float* thb = (const float*)d_in[10];
    const float* phw = (const float*)d_in[11]; const float* phb = (const float*)d_in[12];
    const float* Ww  = (const float*)d_in[13]; const float* Wb  = (const float*)d_in[14];
    float* out = (float*)d_out;

    float* W    = (float*)d_ws;
    float* xg   = W;                 // 589824
    float* y1   = W + 589824;        // 147456
    float* y2c  = W + 737280;        // 36864
    float* y3   = W + 774144;        // 9216
    float* txb  = W + 783360;        // 294912
    float* pxb  = W + 1078272;       // 294912
    float* gxb  = W + 1373184;       // 294912
    float* Dp   = W + 1668096;       // 8*9216 = 73728
    float* logD = W + 1741824;       // 9216
    float* att  = W + 1751040;       // 294912
    float* y2p  = W + 2045952;       // 6*294912 = 1769472
    _Float16* txF = (_Float16*)(W + 3815424);   // 294912 f16
    _Float16* pxF = (_Float16*)(W + 3962880);   // 294912 f16
    _Float16* gxF = (_Float16*)(W + 4110336);   // 294912 f16

    // conv partial buffers live in the (not-yet-used) y2p region
    float* cp1 = y2p;                // 4*147456 = 589824
    float* cp2 = y2p + 589824;       // 8*36864  = 294912
    float* cp3 = y2p + 884736;       // 16*9216  = 147456

    // gating branch (reads ORIGINAL x), ci-split for occupancy
    conv3x3_part<96, 48, 16><<<dim3(9, CC, 4),  256, 0, stream>>>(x,   d1w, cp1);
    conv_merge<4, 2304, 1><<<576, 256, 0, stream>>>(cp1, d1b, y1);
    conv3x3_part<48, 24, 8><<<dim3(3, CC, 8),  192, 0, stream>>>(y1,  d2w, cp2);
    conv_merge<8, 576, 1><<<144, 256, 0, stream>>>(cp2, d2b, y2c);
    conv3x3_part<24, 12, 4><<<dim3(1, CC, 16), 192, 0, stream>>>(y2c, d3w, cp3);
    conv_merge<16, 144, 0><<<36, 256, 0, stream>>>(cp3, d3b, y3);
    gate_kernel<<<2304, 256, 0, stream>>>(x, y3, xg);

    // 1x1 projections (f32)
    conv1x1_3<<<dim3(36, CIN, 3), 256, 0, stream>>>(xg, gw, gb, thw, thb, phw, phb,
                                                    gxb, txb, pxb);
    // fragment repack to f16
    repackAB<<<dim3(144, 2), 256, 0, stream>>>(txb, pxb, txF, pxF);
    repackG<<<144, 256, 0, stream>>>(gxb, gxF);

    // attention via MFMA
    phase1<<<dim3(144, NCH1), 256, 0, stream>>>(txF, pxF, Dp);
    mergeD<<<36, 256, 0, stream>>>(Dp, logD);
    phase2<<<dim3(144, NCH2), 256, 0, stream>>>(txF, pxF, gxF, logD, y2p);
    mergeY2<<<1152, 256, 0, stream>>>(y2p, att);

    // output
    final_conv<<<dim3(36, CC), 256, 0, stream>>>(att, Ww, Wb, xg, out);
}

// Round 5
// 132.794 us; speedup vs baseline: 3.0547x; 1.1610x over previous
//
#include <hip/hip_runtime.h>
#include <math.h>

#define NTOK 9216      // 96*96 tokens
#define CIN  32        // inner channels
#define CC   64        // outer channels
#define NCH1 8         // phase1 n-chunks
#define NCH2 6         // phase2 m-chunks
#define NT1  72        // n-tiles (16-wide) per phase1 chunk: 576/8
#define MS2  48        // m-steps (32-wide) per phase2 chunk: 9216/6/32
#define LOG2E 1.4426950408889634f
#define C1INIT (-17.312340490667560f)   // -12*log2e
#define C2INIT (-9.3123404906675595f)   // -12*log2e + 8  (the +8 = *256 f16-underflow guard)

typedef _Float16 half8 __attribute__((ext_vector_type(8)));
typedef float    f32x4 __attribute__((ext_vector_type(4)));

static __device__ __forceinline__ float fexp2(float x) {
#if __has_builtin(__builtin_amdgcn_exp2f)
    return __builtin_amdgcn_exp2f(x);
#else
    return exp2f(x);
#endif
}

// ---------------- conv1: 3x3 s2 p1, 2 output px/thread, partial over ci ----------------
// grid (6, 64, 8), block 192. thread -> (oh = bx*8 + t/24, ow pair 2q,2q+1), q = t%24.
__global__ void conv3x3_pair96(const float* __restrict__ in, const float* __restrict__ w,
                               float* __restrict__ outp) {
    const int t = threadIdx.x;
    const int q = t % 24, ohl = t / 24;
    const int oh = blockIdx.x * 8 + ohl;
    const int oc = blockIdx.y, grp = blockIdx.z;
    const int ci0 = grp * 8;
    float acc0 = 0.f, acc1 = 0.f;
    const int iwl = 4 * q - 1;
    #pragma unroll
    for (int ci = 0; ci < 8; ++ci) {
        const float* ip = in + (ci0 + ci) * 96 * 96;
        const float* wp = w + oc * CC * 9 + (ci0 + ci) * 9;
        #pragma unroll
        for (int kh = 0; kh < 3; ++kh) {
            int ih = oh * 2 - 1 + kh;
            if (ih < 0) continue;            // ih <= 95 always
            const float* rp = ip + ih * 96;
            float ls = (iwl >= 0) ? rp[iwl] : 0.f;
            float4 f4 = *(const float4*)(rp + 4 * q);
            float w0 = wp[kh * 3], w1 = wp[kh * 3 + 1], w2 = wp[kh * 3 + 2];
            acc0 = fmaf(ls,   w0, acc0);
            acc0 = fmaf(f4.x, w1, acc0);
            acc0 = fmaf(f4.y, w2, acc0);
            acc1 = fmaf(f4.y, w0, acc1);
            acc1 = fmaf(f4.z, w1, acc1);
            acc1 = fmaf(f4.w, w2, acc1);
        }
    }
    float2 r = make_float2(acc0, acc1);
    *(float2*)(outp + grp * (CC * 2304) + oc * 2304 + oh * 48 + 2 * q) = r;
}

// ---------------- generic small conv 3x3 s2 p1: partial over ci-groups ----------------
template<int HIN, int HOUT, int CIG>
__global__ void conv3x3_part(const float* __restrict__ in, const float* __restrict__ w,
                             float* __restrict__ outp) {
    const int p = blockIdx.x * blockDim.x + threadIdx.x;
    if (p >= HOUT * HOUT) return;
    const int oc = blockIdx.y, grp = blockIdx.z;
    const int oh = p / HOUT, ow = p % HOUT;
    const int ci0 = grp * CIG;
    float acc = 0.f;
    #pragma unroll
    for (int ci = 0; ci < CIG; ++ci) {
        const float* ip = in + (ci0 + ci) * HIN * HIN;
        const float* wp = w + oc * CC * 9 + (ci0 + ci) * 9;
        #pragma unroll
        for (int kh = 0; kh < 3; ++kh) {
            int ih = oh * 2 - 1 + kh;
            bool okh = (unsigned)ih < (unsigned)HIN;
            #pragma unroll
            for (int kw = 0; kw < 3; ++kw) {
                int iw = ow * 2 - 1 + kw;
                float v = (okh && (unsigned)iw < (unsigned)HIN) ? ip[ih * HIN + iw] : 0.f;
                acc = fmaf(v, wp[kh * 3 + kw], acc);
            }
        }
    }
    outp[grp * (CC * HOUT * HOUT) + oc * HOUT * HOUT + p] = acc;
}

// ---------------- merge conv partials + bias + (leaky)relu ----------------
template<int NG, int HW, int LRELU>
__global__ void conv_merge(const float* __restrict__ parts, const float* __restrict__ b,
                           float* __restrict__ out) {
    int idx = blockIdx.x * 256 + threadIdx.x;   // CC*HW total
    int oc = idx / HW;
    float acc = b[oc];
    #pragma unroll
    for (int g = 0; g < NG; ++g)
        acc += parts[g * (CC * HW) + idx];
    if (LRELU) acc = acc >= 0.f ? acc : 0.2f * acc;
    out[idx] = acc;
}

// ---------------- bilinear 12->96 upsample + sigmoid gate ----------------
__global__ void gate_kernel(const float* __restrict__ x, const float* __restrict__ y3,
                            float* __restrict__ xg) {
    int idx = blockIdx.x * 256 + threadIdx.x;   // 64*96*96
    int c = idx / (96 * 96);
    int p = idx % (96 * 96);
    int h = p / 96, w = p % 96;
    float fh = (h + 0.5f) * 0.125f - 0.5f;
    float fw = (w + 0.5f) * 0.125f - 0.5f;
    int h0 = (int)floorf(fh); float ah = fh - (float)h0;
    int w0 = (int)floorf(fw); float aw = fw - (float)w0;
    int h0c = min(max(h0, 0), 11), h1c = min(max(h0 + 1, 0), 11);
    int w0c = min(max(w0, 0), 11), w1c = min(max(w0 + 1, 0), 11);
    const float* yp = y3 + c * 144;
    float v = (1.f - ah) * ((1.f - aw) * yp[h0c * 12 + w0c] + aw * yp[h0c * 12 + w1c])
            +         ah * ((1.f - aw) * yp[h1c * 12 + w0c] + aw * yp[h1c * 12 + w1c]);
    float sg = 1.f / (1.f + __expf(-v));
    xg[idx] = sg * x[idx];
}

// ---------------- fused 1x1 convs: g, theta(*log2e), phi in one pass ----------------
__global__ void conv1x1_fused(const float* __restrict__ xg,
                              const float* __restrict__ gw, const float* __restrict__ gb,
                              const float* __restrict__ thw, const float* __restrict__ thb,
                              const float* __restrict__ phw, const float* __restrict__ phb,
                              float* __restrict__ gx, float* __restrict__ tx,
                              float* __restrict__ px) {
    int ci = blockIdx.y;
    int n = blockIdx.x * 256 + threadIdx.x;
    float ag = gb[ci], at = thb[ci], ap = phb[ci];
    #pragma unroll 8
    for (int c = 0; c < CC; ++c) {
        float v = xg[c * NTOK + n];
        ag = fmaf(gw[ci * CC + c],  v, ag);
        at = fmaf(thw[ci * CC + c], v, at);
        ap = fmaf(phw[ci * CC + c], v, ap);
    }
    gx[ci * NTOK + n] = ag;
    tx[ci * NTOK + n] = at * LOG2E;   // fold log2e into theta -> scores in log2 domain
    px[ci * NTOK + n] = ap;
}

// ---------------- repack tx/px (f32 [32][NTOK]) -> fragment-packed f16 ----------------
__global__ void repackAB(const float* __restrict__ tx, const float* __restrict__ px,
                         _Float16* __restrict__ txF, _Float16* __restrict__ pxF) {
    const float* src = blockIdx.y ? px : tx;
    _Float16* dst    = blockIdx.y ? pxF : txF;
    int gid = blockIdx.x * 256 + threadIdx.x;   // 576 tiles * 64 lanes = 36864
    int t = gid >> 6, l = gid & 63;
    int n = t * 16 + (l & 15);
    int khi = (l >> 4) * 4;
    half8 v;
    #pragma unroll
    for (int e = 0; e < 8; ++e) {
        int c = (e >> 2) * 16 + khi + (e & 3);
        v[e] = (_Float16)src[c * NTOK + n];
    }
    *(half8*)(dst + gid * 8) = v;
}

// ---------------- phase 1: Dp[m] = sum_n exp(s-12), MFMA, C-init carries shift ----------------
__global__ __launch_bounds__(256) void phase1(const _Float16* __restrict__ txF,
                                              const _Float16* __restrict__ pxF,
                                              float* __restrict__ Dp) {
    int w = threadIdx.x >> 6, l = threadIdx.x & 63;
    int mtile = blockIdx.x * 4 + w;           // 0..575
    half8 pf = *(const half8*)(pxF + mtile * 512 + l * 8);
    f32x4 cini = {C1INIT, C1INIT, C1INIT, C1INIT};
    float dsum[4] = {0.f, 0.f, 0.f, 0.f};
    int nt0 = blockIdx.y * NT1;
    for (int i = 0; i < NT1; ++i) {
        half8 tf = *(const half8*)(txF + (nt0 + i) * 512 + l * 8);
        f32x4 s = __builtin_amdgcn_mfma_f32_16x16x32_f16(pf, tf, cini, 0, 0, 0);
        #pragma unroll
        for (int r = 0; r < 4; ++r)
            dsum[r] += fexp2(s[r]);
    }
    #pragma unroll
    for (int off = 1; off < 16; off <<= 1)
        #pragma unroll
        for (int r = 0; r < 4; ++r)
            dsum[r] += __shfl_xor(dsum[r], off);
    if ((l & 15) == 0) {
        int m = mtile * 16 + (l >> 4) * 4;
        #pragma unroll
        for (int r = 0; r < 4; ++r)
            Dp[blockIdx.y * NTOK + m + r] = dsum[r];
    }
}

// ---------------- merge D partials -> invD ----------------
__global__ void mergeD(const float* __restrict__ Dp, float* __restrict__ invD) {
    int m = blockIdx.x * 256 + threadIdx.x;
    float D = 0.f;
    #pragma unroll
    for (int ch = 0; ch < NCH1; ++ch) D += Dp[ch * NTOK + m];
    invD[m] = 1.0f / D;
}

// ---------------- repack gx/D -> B-fragment-packed f16: [mt32][ct2][64][8] ----------------
__global__ void repackG(const float* __restrict__ gx, const float* __restrict__ invD,
                        _Float16* __restrict__ gxF) {
    __shared__ float lds[CIN][65];
    __shared__ float idl[64];
    int m0 = blockIdx.x * 64;
    int tid = threadIdx.x;
    for (int idx = tid; idx < CIN * 64; idx += 256)
        lds[idx >> 6][idx & 63] = gx[(idx >> 6) * NTOK + m0 + (idx & 63)];
    if (tid < 64) idl[tid] = invD[m0 + tid];
    __syncthreads();
    int mt = tid >> 7;            // 0..1 (m-32 subtile)
    int slot = tid & 127;
    int ct = slot >> 6;           // c-tile 0..1
    int l  = slot & 63;
    int khi = (l >> 4) * 4;
    int c = ct * 16 + (l & 15);
    half8 v;
    #pragma unroll
    for (int e = 0; e < 8; ++e) {
        int mloc = mt * 32 + (e >> 2) * 16 + khi + (e & 3);
        v[e] = (_Float16)(lds[c][mloc] * idl[mloc]);
    }
    int tile = (blockIdx.x * 2 + mt) * 2 + ct;
    *(half8*)(gxF + tile * 512 + l * 8) = v;
}

// ---------------- phase 2: y2[c,n] = sum_m 256*exp(s-12) * gd[c,m], /256 at write ----------------
__global__ __launch_bounds__(256) void phase2(const _Float16* __restrict__ txF,
                                              const _Float16* __restrict__ pxF,
                                              const _Float16* __restrict__ gxF,
                                              float* __restrict__ y2p) {
    int w = threadIdx.x >> 6, l = threadIdx.x & 63;
    int ntile = blockIdx.x * 4 + w;           // 0..575
    half8 tf = *(const half8*)(txF + ntile * 512 + l * 8);
    int khi = (l >> 4) * 4;
    f32x4 zero = {0.f, 0.f, 0.f, 0.f};
    f32x4 cini = {C2INIT, C2INIT, C2INIT, C2INIT};
    f32x4 acc0 = zero, acc1 = zero;
    int mbase = blockIdx.y * (NTOK / NCH2);
    for (int ms = 0; ms < MS2; ++ms) {
        int m0 = mbase + ms * 32;
        int mt16 = m0 >> 4;
        half8 pf0 = *(const half8*)(pxF + mt16 * 512 + l * 8);
        half8 pf1 = *(const half8*)(pxF + (mt16 + 1) * 512 + l * 8);
        f32x4 s0 = __builtin_amdgcn_mfma_f32_16x16x32_f16(pf0, tf, cini, 0, 0, 0);
        f32x4 s1 = __builtin_amdgcn_mfma_f32_16x16x32_f16(pf1, tf, cini, 0, 0, 0);
        half8 ff;
        #pragma unroll
        for (int r = 0; r < 4; ++r) {
            ff[r]     = (_Float16)fexp2(s0[r]);
            ff[4 + r] = (_Float16)fexp2(s1[r]);
        }
        int gt = (m0 >> 5) * 2;
        half8 gf0 = *(const half8*)(gxF + gt * 512 + l * 8);
        half8 gf1 = *(const half8*)(gxF + (gt + 1) * 512 + l * 8);
        acc0 = __builtin_amdgcn_mfma_f32_16x16x32_f16(ff, gf0, acc0, 0, 0, 0);
        acc1 = __builtin_amdgcn_mfma_f32_16x16x32_f16(ff, gf1, acc1, 0, 0, 0);
    }
    float* base = y2p + blockIdx.y * (CIN * NTOK);
    int n = ntile * 16 + khi;
    #pragma unroll
    for (int r = 0; r < 4; ++r) {
        base[(l & 15) * NTOK + n + r]        = acc0[r] * 0.00390625f;
        base[(16 + (l & 15)) * NTOK + n + r] = acc1[r] * 0.00390625f;
    }
}

// ---------------- merge y2 partials ----------------
__global__ void mergeY2(const float* __restrict__ y2p, float* __restrict__ att) {
    int idx = blockIdx.x * 256 + threadIdx.x;   // 32*9216
    float s = 0.f;
    #pragma unroll
    for (int ch = 0; ch < NCH2; ++ch) s += y2p[ch * (CIN * NTOK) + idx];
    att[idx] = s;
}

// ---------------- final 1x1 conv + residual ----------------
__global__ void final_conv(const float* __restrict__ att, const float* __restrict__ Ww,
                           const float* __restrict__ Wb, const float* __restrict__ xg,
                           float* __restrict__ out) {
    int co = blockIdx.y;
    int n = blockIdx.x * 256 + threadIdx.x;
    float acc = Wb[co];
    #pragma unroll
    for (int ci = 0; ci < CIN; ++ci)
        acc = fmaf(Ww[co * CIN + ci], att[ci * NTOK + n], acc);
    out[co * NTOK + n] = acc + xg[co * NTOK + n];
}

extern "C" void kernel_launch(void* const* d_in, const int* in_sizes, int n_in,
                              void* d_out, int out_size, void* d_ws, size_t ws_size,
                              hipStream_t stream) {
    const float* x   = (const float*)d_in[0];
    const float* d1w = (const float*)d_in[1];  const float* d1b = (const float*)d_in[2];
    const float* d2w = (const float*)d_in[3];  const float* d2b = (const float*)d_in[4];
    const float* d3w = (const float*)d_in[5];  const float* d3b = (const float*)d_in[6];
    const float* gw  = (const float*)d_in[7];  const float* gb  = (const float*)d_in[8];
    const float* thw = (const float*)d_in[9];  const float* thb = (const float*)d_in[10];
    const float* phw = (const float*)d_in[11]; const float* phb = (const float*)d_in[12];
    const float* Ww  = (const float*)d_in[13]; const float* Wb  = (const float*)d_in[14];
    float* out = (float*)d_out;

    float* W    = (float*)d_ws;
    float* xg   = W;                 // 589824
    float* y1   = W + 589824;        // 147456
    float* y2c  = W + 737280;        // 36864
    float* y3   = W + 774144;        // 9216
    float* txb  = W + 783360;        // 294912
    float* pxb  = W + 1078272;       // 294912
    float* gxb  = W + 1373184;       // 294912
    float* Dp   = W + 1668096;       // 8*9216 = 73728
    float* invD = W + 1741824;       // 9216
    float* att  = W + 1751040;       // 294912
    float* y2p  = W + 2045952;       // 6*294912 = 1769472 (ends 3815424)
    _Float16* txF = (_Float16*)(W + 3815424);   // 294912 f16
    _Float16* pxF = (_Float16*)(W + 3962880);   // 294912 f16
    _Float16* gxF = (_Float16*)(W + 4110336);   // 294912 f16 (end 4257792 fl = 17.0 MB)

    // conv partial buffers: reuse y2p+ region (dead until phase2; txF/pxF written later)
    float* cp1 = y2p;                 // 8*147456 = 1179648
    float* cp2 = y2p + 1179648;       // 16*36864 = 589824
    float* cp3 = y2p + 1769472;       // 16*9216  = 147456 (spills into txF region: ok, temporal)

    // gating branch (reads ORIGINAL x), ci-split for occupancy
    conv3x3_pair96<<<dim3(6, CC, 8), 192, 0, stream>>>(x, d1w, cp1);
    conv_merge<8, 2304, 1><<<576, 256, 0, stream>>>(cp1, d1b, y1);
    conv3x3_part<48, 24, 4><<<dim3(3, CC, 16), 192, 0, stream>>>(y1,  d2w, cp2);
    conv_merge<16, 576, 1><<<144, 256, 0, stream>>>(cp2, d2b, y2c);
    conv3x3_part<24, 12, 4><<<dim3(1, CC, 16), 192, 0, stream>>>(y2c, d3w, cp3);
    conv_merge<16, 144, 0><<<36, 256, 0, stream>>>(cp3, d3b, y3);
    gate_kernel<<<2304, 256, 0, stream>>>(x, y3, xg);

    // fused 1x1 projections (theta scaled by log2e)
    conv1x1_fused<<<dim3(36, CIN), 256, 0, stream>>>(xg, gw, gb, thw, thb, phw, phb,
                                                     gxb, txb, pxb);
    // fragment repack to f16
    repackAB<<<dim3(144, 2), 256, 0, stream>>>(txb, pxb, txF, pxF);

    // attention via MFMA
    phase1<<<dim3(144, NCH1), 256, 0, stream>>>(txF, pxF, Dp);
    mergeD<<<36, 256, 0, stream>>>(Dp, invD);
    repackG<<<144, 256, 0, stream>>>(gxb, invD, gxF);
    phase2<<<dim3(144, NCH2), 256, 0, stream>>>(txF, pxF, gxF, y2p);
    mergeY2<<<1152, 256, 0, stream>>>(y2p, att);

    // output
    final_conv<<<dim3(36, CC), 256, 0, stream>>>(att, Ww, Wb, xg, out);
}

// Round 6
// 122.255 us; speedup vs baseline: 3.3181x; 1.0862x over previous
//
#include <hip/hip_runtime.h>
#include <math.h>

#define NTOK 9216      // 96*96 tokens
#define CIN  32        // inner channels
#define CC   64        // outer channels
#define NCH1 16        // phase1 n-chunks
#define NT1S 36        // n-tile steps per phase1 chunk: 576/16
#define NCH2 12        // phase2 m-chunks
#define MS2  24        // m-steps (32-wide) per phase2 chunk: 9216/12/32
#define LOG2E 1.4426950408889634f
#define C1INIT (-17.312340490667560f)   // -12*log2e
#define C2INIT (-9.3123404906675595f)   // -12*log2e + 8  (the +8 = *256 f16-underflow guard)

typedef _Float16 half8 __attribute__((ext_vector_type(8)));
typedef float    f32x4 __attribute__((ext_vector_type(4)));

static __device__ __forceinline__ float fexp2(float x) {
#if __has_builtin(__builtin_amdgcn_exp2f)
    return __builtin_amdgcn_exp2f(x);
#else
    return exp2f(x);
#endif
}

// ---------------- conv1: 3x3 s2 p1, 4 output px/thread, partial over ci ----------------
// grid (3, 64, 8), block 192. thread -> (oh = bx*16 + t/12, ow quad 4q..4q+3), q = t%12.
__global__ void conv3x3_quad96(const float* __restrict__ in, const float* __restrict__ w,
                               float* __restrict__ outp) {
    const int t = threadIdx.x;
    const int q = t % 12, ohl = t / 12;
    const int oh = blockIdx.x * 16 + ohl;
    const int oc = blockIdx.y, grp = blockIdx.z;
    const int ci0 = grp * 8;
    float a0 = 0.f, a1 = 0.f, a2 = 0.f, a3 = 0.f;
    const int iwl = 8 * q - 1;
    #pragma unroll
    for (int ci = 0; ci < 8; ++ci) {
        const float* ip = in + (ci0 + ci) * 96 * 96;
        const float* wp = w + oc * CC * 9 + (ci0 + ci) * 9;
        #pragma unroll
        for (int kh = 0; kh < 3; ++kh) {
            int ih = oh * 2 - 1 + kh;
            if (ih < 0) continue;            // ih <= 95 always
            const float* rp = ip + ih * 96;
            float ls = (q > 0) ? rp[iwl] : 0.f;
            float4 fa = *(const float4*)(rp + 8 * q);
            float4 fb = *(const float4*)(rp + 8 * q + 4);
            float w0 = wp[kh * 3], w1 = wp[kh * 3 + 1], w2 = wp[kh * 3 + 2];
            a0 = fmaf(ls,   w0, fmaf(fa.x, w1, fmaf(fa.y, w2, a0)));
            a1 = fmaf(fa.y, w0, fmaf(fa.z, w1, fmaf(fa.w, w2, a1)));
            a2 = fmaf(fa.w, w0, fmaf(fb.x, w1, fmaf(fb.y, w2, a2)));
            a3 = fmaf(fb.y, w0, fmaf(fb.z, w1, fmaf(fb.w, w2, a3)));
        }
    }
    float4 r = make_float4(a0, a1, a2, a3);
    *(float4*)(outp + grp * (CC * 2304) + oc * 2304 + oh * 48 + 4 * q) = r;
}

// ---------------- generic small conv 3x3 s2 p1: partial over ci-groups ----------------
template<int HIN, int HOUT, int CIG>
__global__ void conv3x3_part(const float* __restrict__ in, const float* __restrict__ w,
                             float* __restrict__ outp) {
    const int p = blockIdx.x * blockDim.x + threadIdx.x;
    if (p >= HOUT * HOUT) return;
    const int oc = blockIdx.y, grp = blockIdx.z;
    const int oh = p / HOUT, ow = p % HOUT;
    const int ci0 = grp * CIG;
    float acc = 0.f;
    #pragma unroll
    for (int ci = 0; ci < CIG; ++ci) {
        const float* ip = in + (ci0 + ci) * HIN * HIN;
        const float* wp = w + oc * CC * 9 + (ci0 + ci) * 9;
        #pragma unroll
        for (int kh = 0; kh < 3; ++kh) {
            int ih = oh * 2 - 1 + kh;
            bool okh = (unsigned)ih < (unsigned)HIN;
            #pragma unroll
            for (int kw = 0; kw < 3; ++kw) {
                int iw = ow * 2 - 1 + kw;
                float v = (okh && (unsigned)iw < (unsigned)HIN) ? ip[ih * HIN + iw] : 0.f;
                acc = fmaf(v, wp[kh * 3 + kw], acc);
            }
        }
    }
    outp[grp * (CC * HOUT * HOUT) + oc * HOUT * HOUT + p] = acc;
}

// ---------------- merge conv partials + bias + (leaky)relu ----------------
template<int NG, int HW, int LRELU>
__global__ void conv_merge(const float* __restrict__ parts, const float* __restrict__ b,
                           float* __restrict__ out) {
    int idx = blockIdx.x * 256 + threadIdx.x;   // CC*HW total
    int oc = idx / HW;
    float acc = b[oc];
    #pragma unroll
    for (int g = 0; g < NG; ++g)
        acc += parts[g * (CC * HW) + idx];
    if (LRELU) acc = acc >= 0.f ? acc : 0.2f * acc;
    out[idx] = acc;
}

// ---------------- bilinear 12->96 upsample + sigmoid gate ----------------
__global__ void gate_kernel(const float* __restrict__ x, const float* __restrict__ y3,
                            float* __restrict__ xg) {
    int idx = blockIdx.x * 256 + threadIdx.x;   // 64*96*96
    int c = idx / (96 * 96);
    int p = idx % (96 * 96);
    int h = p / 96, w = p % 96;
    float fh = (h + 0.5f) * 0.125f - 0.5f;
    float fw = (w + 0.5f) * 0.125f - 0.5f;
    int h0 = (int)floorf(fh); float ah = fh - (float)h0;
    int w0 = (int)floorf(fw); float aw = fw - (float)w0;
    int h0c = min(max(h0, 0), 11), h1c = min(max(h0 + 1, 0), 11);
    int w0c = min(max(w0, 0), 11), w1c = min(max(w0 + 1, 0), 11);
    const float* yp = y3 + c * 144;
    float v = (1.f - ah) * ((1.f - aw) * yp[h0c * 12 + w0c] + aw * yp[h0c * 12 + w1c])
            +         ah * ((1.f - aw) * yp[h1c * 12 + w0c] + aw * yp[h1c * 12 + w1c]);
    float sg = 1.f / (1.f + __expf(-v));
    xg[idx] = sg * x[idx];
}

// ---------------- fused 1x1 convs: g, theta(*log2e), phi in one pass ----------------
__global__ void conv1x1_fused(const float* __restrict__ xg,
                              const float* __restrict__ gw, const float* __restrict__ gb,
                              const float* __restrict__ thw, const float* __restrict__ thb,
                              const float* __restrict__ phw, const float* __restrict__ phb,
                              float* __restrict__ gx, float* __restrict__ tx,
                              float* __restrict__ px) {
    int ci = blockIdx.y;
    int n = blockIdx.x * 256 + threadIdx.x;
    float ag = gb[ci], at = thb[ci], ap = phb[ci];
    #pragma unroll 8
    for (int c = 0; c < CC; ++c) {
        float v = xg[c * NTOK + n];
        ag = fmaf(gw[ci * CC + c],  v, ag);
        at = fmaf(thw[ci * CC + c], v, at);
        ap = fmaf(phw[ci * CC + c], v, ap);
    }
    gx[ci * NTOK + n] = ag;
    tx[ci * NTOK + n] = at * LOG2E;   // fold log2e into theta -> scores in log2 domain
    px[ci * NTOK + n] = ap;
}

// ---------------- repack tx/px (f32 [32][NTOK]) -> fragment-packed f16 ----------------
__global__ void repackAB(const float* __restrict__ tx, const float* __restrict__ px,
                         _Float16* __restrict__ txF, _Float16* __restrict__ pxF) {
    const float* src = blockIdx.y ? px : tx;
    _Float16* dst    = blockIdx.y ? pxF : txF;
    int gid = blockIdx.x * 256 + threadIdx.x;   // 576 tiles * 64 lanes = 36864
    int t = gid >> 6, l = gid & 63;
    int n = t * 16 + (l & 15);
    int khi = (l >> 4) * 4;
    half8 v;
    #pragma unroll
    for (int e = 0; e < 8; ++e) {
        int c = (e >> 2) * 16 + khi + (e & 3);
        v[e] = (_Float16)src[c * NTOK + n];
    }
    *(half8*)(dst + gid * 8) = v;
}

// ---------------- phase 1: Dp[m] = sum_n exp2(s'), 4 m-tiles per wave ----------------
__global__ __launch_bounds__(256) void phase1(const _Float16* __restrict__ txF,
                                              const _Float16* __restrict__ pxF,
                                              float* __restrict__ Dp) {
    int w = threadIdx.x >> 6, l = threadIdx.x & 63;
    int mtile0 = (blockIdx.x * 4 + w) * 4;     // 4 consecutive m-tiles per wave
    half8 pf[4];
    #pragma unroll
    for (int j = 0; j < 4; ++j)
        pf[j] = *(const half8*)(pxF + (mtile0 + j) * 512 + l * 8);
    f32x4 cini = {C1INIT, C1INIT, C1INIT, C1INIT};
    float dsum[4][4] = {};
    int nt0 = blockIdx.y * NT1S;
    for (int i = 0; i < NT1S; ++i) {
        half8 tf = *(const half8*)(txF + (nt0 + i) * 512 + l * 8);
        #pragma unroll
        for (int j = 0; j < 4; ++j) {
            f32x4 s = __builtin_amdgcn_mfma_f32_16x16x32_f16(pf[j], tf, cini, 0, 0, 0);
            #pragma unroll
            for (int r = 0; r < 4; ++r)
                dsum[j][r] += fexp2(s[r]);
        }
    }
    #pragma unroll
    for (int off = 1; off < 16; off <<= 1)
        #pragma unroll
        for (int j = 0; j < 4; ++j)
            #pragma unroll
            for (int r = 0; r < 4; ++r)
                dsum[j][r] += __shfl_xor(dsum[j][r], off);
    if ((l & 15) == 0) {
        #pragma unroll
        for (int j = 0; j < 4; ++j) {
            int m = (mtile0 + j) * 16 + (l >> 4) * 4;
            #pragma unroll
            for (int r = 0; r < 4; ++r)
                Dp[blockIdx.y * NTOK + m + r] = dsum[j][r];
        }
    }
}

// ---------------- repack gx/D -> B-fragment f16 [mt32][ct2][64][8]; merges Dp inline ----------------
__global__ void repackG(const float* __restrict__ gx, const float* __restrict__ Dp,
                        _Float16* __restrict__ gxF) {
    __shared__ float lds[CIN][65];
    __shared__ float idl[64];
    int m0 = blockIdx.x * 64;
    int tid = threadIdx.x;
    for (int idx = tid; idx < CIN * 64; idx += 256)
        lds[idx >> 6][idx & 63] = gx[(idx >> 6) * NTOK + m0 + (idx & 63)];
    if (tid < 64) {
        float D = 0.f;
        #pragma unroll
        for (int ch = 0; ch < NCH1; ++ch) D += Dp[ch * NTOK + m0 + tid];
        idl[tid] = 1.0f / D;
    }
    __syncthreads();
    int mt = tid >> 7;            // 0..1 (m-32 subtile)
    int slot = tid & 127;
    int ct = slot >> 6;           // c-tile 0..1
    int l  = slot & 63;
    int khi = (l >> 4) * 4;
    int c = ct * 16 + (l & 15);
    half8 v;
    #pragma unroll
    for (int e = 0; e < 8; ++e) {
        int mloc = mt * 32 + (e >> 2) * 16 + khi + (e & 3);
        v[e] = (_Float16)(lds[c][mloc] * idl[mloc]);
    }
    int tile = (blockIdx.x * 2 + mt) * 2 + ct;
    *(half8*)(gxF + tile * 512 + l * 8) = v;
}

// ---------------- phase 2: y2 = sum_m 256*exp2(s')*gd, 4 n-tiles per wave ----------------
__global__ __launch_bounds__(256) void phase2(const _Float16* __restrict__ txF,
                                              const _Float16* __restrict__ pxF,
                                              const _Float16* __restrict__ gxF,
                                              float* __restrict__ y2p) {
    int w = threadIdx.x >> 6, l = threadIdx.x & 63;
    int ntile0 = (blockIdx.x * 4 + w) * 4;     // 4 consecutive n-tiles per wave
    half8 tf[4];
    #pragma unroll
    for (int j = 0; j < 4; ++j)
        tf[j] = *(const half8*)(txF + (ntile0 + j) * 512 + l * 8);
    int khi = (l >> 4) * 4;
    f32x4 zero = {0.f, 0.f, 0.f, 0.f};
    f32x4 cini = {C2INIT, C2INIT, C2INIT, C2INIT};
    f32x4 acc[4][2];
    #pragma unroll
    for (int j = 0; j < 4; ++j) { acc[j][0] = zero; acc[j][1] = zero; }
    int mbase = blockIdx.y * (NTOK / NCH2);
    for (int ms = 0; ms < MS2; ++ms) {
        int m0 = mbase + ms * 32;
        int mt16 = m0 >> 4;
        half8 pf0 = *(const half8*)(pxF + mt16 * 512 + l * 8);
        half8 pf1 = *(const half8*)(pxF + (mt16 + 1) * 512 + l * 8);
        int gt = (m0 >> 5) * 2;
        half8 gf0 = *(const half8*)(gxF + gt * 512 + l * 8);
        half8 gf1 = *(const half8*)(gxF + (gt + 1) * 512 + l * 8);
        #pragma unroll
        for (int j = 0; j < 4; ++j) {
            f32x4 s0 = __builtin_amdgcn_mfma_f32_16x16x32_f16(pf0, tf[j], cini, 0, 0, 0);
            f32x4 s1 = __builtin_amdgcn_mfma_f32_16x16x32_f16(pf1, tf[j], cini, 0, 0, 0);
            half8 ff;
            #pragma unroll
            for (int r = 0; r < 4; ++r) {
                ff[r]     = (_Float16)fexp2(s0[r]);
                ff[4 + r] = (_Float16)fexp2(s1[r]);
            }
            acc[j][0] = __builtin_amdgcn_mfma_f32_16x16x32_f16(ff, gf0, acc[j][0], 0, 0, 0);
            acc[j][1] = __builtin_amdgcn_mfma_f32_16x16x32_f16(ff, gf1, acc[j][1], 0, 0, 0);
        }
    }
    float* base = y2p + blockIdx.y * (CIN * NTOK);
    #pragma unroll
    for (int j = 0; j < 4; ++j) {
        int n = (ntile0 + j) * 16 + khi;
        #pragma unroll
        for (int r = 0; r < 4; ++r) {
            base[(l & 15) * NTOK + n + r]        = acc[j][0][r] * 0.00390625f;
            base[(16 + (l & 15)) * NTOK + n + r] = acc[j][1][r] * 0.00390625f;
        }
    }
}

// ---------------- merge y2 partials ----------------
__global__ void mergeY2(const float* __restrict__ y2p, float* __restrict__ att) {
    int idx = blockIdx.x * 256 + threadIdx.x;   // 32*9216
    float s = 0.f;
    #pragma unroll
    for (int ch = 0; ch < NCH2; ++ch) s += y2p[ch * (CIN * NTOK) + idx];
    att[idx] = s;
}

// ---------------- final 1x1 conv + residual ----------------
__global__ void final_conv(const float* __restrict__ att, const float* __restrict__ Ww,
                           const float* __restrict__ Wb, const float* __restrict__ xg,
                           float* __restrict__ out) {
    int co = blockIdx.y;
    int n = blockIdx.x * 256 + threadIdx.x;
    float acc = Wb[co];
    #pragma unroll
    for (int ci = 0; ci < CIN; ++ci)
        acc = fmaf(Ww[co * CIN + ci], att[ci * NTOK + n], acc);
    out[co * NTOK + n] = acc + xg[co * NTOK + n];
}

extern "C" void kernel_launch(void* const* d_in, const int* in_sizes, int n_in,
                              void* d_out, int out_size, void* d_ws, size_t ws_size,
                              hipStream_t stream) {
    const float* x   = (const float*)d_in[0];
    const float* d1w = (const float*)d_in[1];  const float* d1b = (const float*)d_in[2];
    const float* d2w = (const float*)d_in[3];  const float* d2b = (const float*)d_in[4];
    const float* d3w = (const float*)d_in[5];  const float* d3b = (const float*)d_in[6];
    const float* gw  = (const float*)d_in[7];  const float* gb  = (const float*)d_in[8];
    const float* thw = (const float*)d_in[9];  const float* thb = (const float*)d_in[10];
    const float* phw = (const float*)d_in[11]; const float* phb = (const float*)d_in[12];
    const float* Ww  = (const float*)d_in[13]; const float* Wb  = (const float*)d_in[14];
    float* out = (float*)d_out;

    float* W    = (float*)d_ws;
    float* xg   = W;                 // 589824
    float* y1   = W + 589824;        // 147456 -> 737280
    float* y2c  = W + 737280;        // 36864  -> 774144
    float* y3   = W + 774144;        // 9216   -> 783360
    float* txb  = W + 783360;        // 294912 -> 1078272
    float* pxb  = W + 1078272;       // 294912 -> 1373184
    float* gxb  = W + 1373184;       // 294912 -> 1668096
    float* Dp   = W + 1668096;       // 16*9216 = 147456 -> 1815552
    float* att  = W + 1815552;       // 294912 -> 2110464
    float* y2p  = W + 2110464;       // 12*294912 = 3538944 -> 5649408
    _Float16* txF = (_Float16*)(W + 5649408);   // 294912 f16 (147456 fl) -> 5796864
    _Float16* pxF = (_Float16*)(W + 5796864);   // -> 5944320
    _Float16* gxF = (_Float16*)(W + 5944320);   // -> 6091776 floats = 24.4 MB

    // conv partial buffers: reuse y2p region (dead until phase2)
    float* cp1 = y2p;                 // 8*147456 = 1179648
    float* cp2 = y2p + 1179648;       // 16*36864 = 589824
    float* cp3 = y2p + 1769472;       // 16*9216  = 147456 (total 1916928 < y2p size)

    // gating branch (reads ORIGINAL x), ci-split for occupancy
    conv3x3_quad96<<<dim3(3, CC, 8), 192, 0, stream>>>(x, d1w, cp1);
    conv_merge<8, 2304, 1><<<576, 256, 0, stream>>>(cp1, d1b, y1);
    conv3x3_part<48, 24, 4><<<dim3(3, CC, 16), 192, 0, stream>>>(y1,  d2w, cp2);
    conv_merge<16, 576, 1><<<144, 256, 0, stream>>>(cp2, d2b, y2c);
    conv3x3_part<24, 12, 4><<<dim3(1, CC, 16), 192, 0, stream>>>(y2c, d3w, cp3);
    conv_merge<16, 144, 0><<<36, 256, 0, stream>>>(cp3, d3b, y3);
    gate_kernel<<<2304, 256, 0, stream>>>(x, y3, xg);

    // fused 1x1 projections (theta scaled by log2e)
    conv1x1_fused<<<dim3(36, CIN), 256, 0, stream>>>(xg, gw, gb, thw, thb, phw, phb,
                                                     gxb, txb, pxb);
    // fragment repack to f16
    repackAB<<<dim3(144, 2), 256, 0, stream>>>(txb, pxb, txF, pxF);

    // attention via MFMA (register-blocked 4 tiles/wave)
    phase1<<<dim3(36, NCH1), 256, 0, stream>>>(txF, pxF, Dp);
    repackG<<<144, 256, 0, stream>>>(gxb, Dp, gxF);
    phase2<<<dim3(36, NCH2), 256, 0, stream>>>(txF, pxF, gxF, y2p);
    mergeY2<<<1152, 256, 0, stream>>>(y2p, att);

    // output
    final_conv<<<dim3(36, CC), 256, 0, stream>>>(att, Ww, Wb, xg, out);
}